// Round 1
// baseline (2753.923 us; speedup 1.0000x reference)
//
#include <hip/hip_runtime.h>
#include <stdint.h>
#include <math.h>

// ---------------- problem constants ----------------
static constexpr int NN = 160000;   // nodes
static constexpr int NE = 640000;   // edges
static constexpr int NG = 8000;     // graphs (20 nodes each, contiguous)
static constexpr int FI0 = 74;      // input feats
static constexpr int FH  = 63;      // hidden
static constexpr int ZST = 64;      // padded z row stride (floats)
static constexpr int NB  = 16;      // nodes per block in layer kernel
static constexpr int BPB = (NN + NB - 1) / NB;   // blocks per bucket = 10000

// ---------------- workspace layout (bytes) ----------------
static constexpr size_t OFF_DEGCNT = 0;                       // 160000 i32
static constexpr size_t OFF_CURSOR = 640000;                  // 160000 i32
static constexpr size_t OFF_BCNT   = 1280000;                 // 16 i32
static constexpr size_t OFF_SPART  = 1280064;                 // 3*256*128 f32 partial stats
static constexpr size_t ZERO_BYTES = 1673280;                 // everything above zeroed
static constexpr size_t OFF_ROWPTR = 1673280;                 // 160001 i32
static constexpr size_t OFF_BLKSUM = 2313472;                 // 512 i32
static constexpr size_t OFF_COL    = 2315520;                 // 640000 i32
static constexpr size_t OFF_BLIST  = 4875520;                 // 10*160000 i32
static constexpr size_t OFF_AFC    = 11275520;                // 3*2*64 f32 (a,c per layer)
static constexpr size_t OFF_WNG2   = 11277056;                // 63*128 f32 folded W_ng
static constexpr size_t OFF_BNG2   = 11309312;                // 128 f32 folded b_ng
static constexpr size_t OFF_Z0     = 11310080;                // 160000*64 f32
static constexpr size_t OFF_Z1     = 52270080;                // 160000*64 f32
// total ~93.2 MB

// ---------------- CSR / degree build ----------------
__global__ void k_degree(const int* __restrict__ dst, int* __restrict__ degcnt) {
    int e = blockIdx.x * 256 + threadIdx.x;
    if (e < NE) atomicAdd(&degcnt[dst[e]], 1);
}

__global__ void k_scan1(const int* __restrict__ degcnt, int* __restrict__ row_ptr,
                        int* __restrict__ blksum) {
    __shared__ int s[1024];
    int t = threadIdx.x;
    int i = blockIdx.x * 1024 + t;
    int v = (i < NN) ? degcnt[i] : 0;
    s[t] = v; __syncthreads();
    for (int off = 1; off < 1024; off <<= 1) {
        int x = (t >= off) ? s[t - off] : 0;
        __syncthreads();
        s[t] += x;
        __syncthreads();
    }
    if (i < NN) row_ptr[i + 1] = s[t];            // local inclusive scan
    if (t == 1023) blksum[blockIdx.x] = s[t];     // block total
}

__global__ void k_scan2(int* __restrict__ blksum, int nblk) {
    __shared__ int s[256];
    int t = threadIdx.x;
    int v = (t < nblk) ? blksum[t] : 0;
    s[t] = v; __syncthreads();
    for (int off = 1; off < 256; off <<= 1) {
        int x = (t >= off) ? s[t - off] : 0;
        __syncthreads();
        s[t] += x;
        __syncthreads();
    }
    if (t < nblk) blksum[t] = s[t] - v;           // exclusive
}

__global__ void k_scan3(int* __restrict__ row_ptr, const int* __restrict__ blksum) {
    int t = threadIdx.x;
    int i = blockIdx.x * 1024 + t;
    if (i < NN) row_ptr[i + 1] += blksum[blockIdx.x];
    if (i == 0) row_ptr[0] = 0;
}

__global__ void k_bucket(const int* __restrict__ degcnt, int* __restrict__ bcnt,
                         int* __restrict__ blist) {
    int n = blockIdx.x * 256 + threadIdx.x;
    if (n >= NN) return;
    int d = degcnt[n];
    int k = (d < 1) ? 0 : ((d > 10) ? 9 : d - 1);   // clip(deg,1,10)-1
    int pos = atomicAdd(&bcnt[k], 1);
    blist[k * NN + pos] = n;
}

__global__ void k_fill(const int* __restrict__ src, const int* __restrict__ dst,
                       const int* __restrict__ row_ptr, int* __restrict__ cursor,
                       int* __restrict__ col) {
    int e = blockIdx.x * 256 + threadIdx.x;
    if (e >= NE) return;
    int d = dst[e];
    int pos = row_ptr[d] + atomicAdd(&cursor[d], 1);
    col[pos] = src[e];
}

// ---------------- NF layer: gather + bucketed matmul + relu + stats ----------------
// block = 256 threads = 4 waves; NB=16 nodes (same degree bucket), 4 per wave.
// grid = 10 * BPB; blocks past a bucket's count exit immediately.
template<int FI, bool AFF>
__global__ void __launch_bounds__(256) k_layer(
    const float* __restrict__ in, int in_stride,
    const float* __restrict__ aff,                 // [2][64]: a, c (folded BN of prev layer)
    const int* __restrict__ row_ptr, const int* __restrict__ col,
    const int* __restrict__ bcnt, const int* __restrict__ blist,
    const float* __restrict__ W,                   // [10][FI][63]
    const float* __restrict__ B,                   // [10][63]
    float* __restrict__ zout,                      // [NN][64] (relu'd, pre-BN)
    float* __restrict__ spart)                     // [256][128] f32 partial stats
{
    int bucket = blockIdx.x / BPB;
    int base   = (blockIdx.x % BPB) * NB;
    int cnt    = bcnt[bucket];
    if (base >= cnt) return;

    __shared__ float sW[FI * 63 + 64];
    __shared__ float sTot[4][80][4];
    __shared__ float sRed[2][4][64];

    int tid = threadIdx.x;
    const float* Wk = W + (size_t)bucket * FI * 63;
    for (int i = tid; i < FI * 63; i += 256) sW[i] = Wk[i];
    __syncthreads();

    int wave = tid >> 6, lane = tid & 63;

    int  nidx[4];
    bool val[4];

    // ---- gather phase: tot = self + sum(neighbors) (+ folded BN affine) ----
    for (int t = 0; t < 4; ++t) {
        int idx = base + wave * 4 + t;
        val[t] = (idx < cnt);
        int n = blist[bucket * NN + (val[t] ? idx : (cnt - 1))];
        nidx[t] = n;
        int rs = row_ptr[n], re = row_ptr[n + 1];
        float t0 = 0.f, t1 = 0.f;
        if (lane < FI)      t0 = in[(size_t)n * in_stride + lane];
        if (FI > 64 && lane + 64 < FI) t1 = in[(size_t)n * in_stride + lane + 64];
        for (int e = rs; e < re; ++e) {
            int s = col[e];
            if (lane < FI)      t0 += in[(size_t)s * in_stride + lane];
            if (FI > 64 && lane + 64 < FI) t1 += in[(size_t)s * in_stride + lane + 64];
        }
        if constexpr (AFF) {
            // tot = a*(z_self + sum z_src) + (deg+1)*c
            float dp1 = (float)(re - rs) + 1.0f;
            if (lane < FI) t0 = aff[lane] * t0 + dp1 * aff[64 + lane];
        }
        sTot[wave][lane][t] = t0;
        if (FI > 64 && lane + 64 < FI) sTot[wave][lane + 64][t] = t1;
    }
    // same-wave LDS write->read: compiler inserts lgkmcnt waits; no barrier needed.

    // ---- matmul: z[o] = b[k][o] + sum_j tot[j]*W[k][j][o], 4 nodes at once ----
    float bterm = (lane < 63) ? B[bucket * 63 + lane] : 0.f;
    float acc[4] = {bterm, bterm, bterm, bterm};
    for (int j = 0; j < FI; ++j) {
        float w = sW[j * 63 + lane];  // lane 63 reads pad garbage; result unused
        float4 tv = *reinterpret_cast<const float4*>(&sTot[wave][j][0]);
        acc[0] = fmaf(tv.x, w, acc[0]);
        acc[1] = fmaf(tv.y, w, acc[1]);
        acc[2] = fmaf(tv.z, w, acc[2]);
        acc[3] = fmaf(tv.w, w, acc[3]);
    }

    // ---- relu, store, per-lane (=per-feature) stats ----
    float lsum = 0.f, lsq = 0.f;
    for (int t = 0; t < 4; ++t) {
        float z = fmaxf(acc[t], 0.f);
        if (val[t] && lane < 63) {
            zout[(size_t)nidx[t] * ZST + lane] = z;
            lsum += z; lsq += z * z;
        }
    }
    sRed[0][wave][lane] = lsum;
    sRed[1][wave][lane] = lsq;
    __syncthreads();
    if (wave == 0 && lane < 63) {
        float s = sRed[0][0][lane] + sRed[0][1][lane] + sRed[0][2][lane] + sRed[0][3][lane];
        float q = sRed[1][0][lane] + sRed[1][1][lane] + sRed[1][2][lane] + sRed[1][3][lane];
        float* sp = spart + (size_t)(blockIdx.x & 255) * 128;
        atomicAdd(&sp[lane], s);
        atomicAdd(&sp[64 + lane], q);
    }
}

// ---------------- BN stats -> affine (a, c) ----------------
__global__ void k_bn(const float* __restrict__ spart, const float* __restrict__ gamma,
                     const float* __restrict__ beta, float* __restrict__ afc) {
    int o = threadIdx.x;
    if (o >= 63) return;
    double s = 0.0, q = 0.0;
    for (int cp = 0; cp < 256; ++cp) {
        s += (double)spart[cp * 128 + o];
        q += (double)spart[cp * 128 + 64 + o];
    }
    double mu  = s / NN;
    double var = q / NN - mu * mu;
    float a = (float)((double)gamma[o] / sqrt(var + 1e-5));
    float c = (float)((double)beta[o] - mu * (double)a);
    afc[o] = a;
    afc[64 + o] = c;
}

// ---------------- fold last BN into W_ng ----------------
__global__ void k_fold(const float* __restrict__ W_ng, const float* __restrict__ b_ng,
                       const float* __restrict__ afc2, float* __restrict__ Wng2,
                       float* __restrict__ bng2) {
    int o = threadIdx.x;   // 128
    float acc = b_ng[o];
    for (int j = 0; j < 63; ++j) {
        float w = W_ng[j * 128 + o];
        Wng2[j * 128 + o] = afc2[j] * w;
        acc = fmaf(afc2[64 + j], w, acc);
    }
    bng2[o] = acc;
}

// ---------------- readout: node->graph GEMM + sum/max + tanh + final GEMM ----------------
// block = 256 threads handles 8 graphs (160 nodes). grid = 1000.
__global__ void __launch_bounds__(256) k_graph(
    const float* __restrict__ Z2, const float* __restrict__ Wng2,
    const float* __restrict__ bng2, const float* __restrict__ W_tr,
    const float* __restrict__ b_tr, float* __restrict__ out)
{
    __shared__ float sWng[63 * 128];
    __shared__ float sT[8][256];
    int tid = threadIdx.x;
    for (int i = tid; i < 63 * 128; i += 256) sWng[i] = Wng2[i];
    __syncthreads();

    int wv = tid >> 6, lane = tid & 63;
    int g0 = blockIdx.x * 8;

    // phase A: each wave does 2 graphs; lane covers o and o+64 of 128 outputs
    for (int gg = 0; gg < 2; ++gg) {
        int gl = wv * 2 + gg;
        const float* zb = Z2 + (size_t)(g0 + gl) * 20 * ZST;
        float acc0[20], acc1[20];
        float b0v = bng2[lane], b1v = bng2[lane + 64];
#pragma unroll
        for (int i = 0; i < 20; ++i) { acc0[i] = b0v; acc1[i] = b1v; }
        for (int j = 0; j < 63; ++j) {
            float w0 = sWng[j * 128 + lane];
            float w1 = sWng[j * 128 + lane + 64];
#pragma unroll
            for (int i = 0; i < 20; ++i) {
                float z = zb[i * ZST + j];   // uniform across lanes -> scalar loads
                acc0[i] = fmaf(z, w0, acc0[i]);
                acc1[i] = fmaf(z, w1, acc1[i]);
            }
        }
        float s0 = 0.f, s1 = 0.f, m0 = -1e30f, m1 = -1e30f;
#pragma unroll
        for (int i = 0; i < 20; ++i) {
            s0 += acc0[i]; s1 += acc1[i];
            m0 = fmaxf(m0, acc0[i]); m1 = fmaxf(m1, acc1[i]);
        }
        sT[gl][lane]       = tanhf(s0);
        sT[gl][lane + 64]  = tanhf(s1);
        sT[gl][128 + lane] = tanhf(m0);
        sT[gl][192 + lane] = tanhf(m1);
    }
    __syncthreads();

    // phase B: out[g][d] = b_tr[d] + sum_q t[g][q] * W_tr[q][d]
    int d = tid;
    float acc[8];
    float bt = b_tr[d];
#pragma unroll
    for (int gl = 0; gl < 8; ++gl) acc[gl] = bt;
    for (int q = 0; q < 256; ++q) {
        float w = W_tr[q * 256 + d];
#pragma unroll
        for (int gl = 0; gl < 8; ++gl) acc[gl] = fmaf(sT[gl][q], w, acc[gl]);
    }
#pragma unroll
    for (int gl = 0; gl < 8; ++gl) out[(size_t)(g0 + gl) * 256 + d] = acc[gl];
}

// ---------------- launch ----------------
extern "C" void kernel_launch(void* const* d_in, const int* in_sizes, int n_in,
                              void* d_out, int out_size, void* d_ws, size_t ws_size,
                              hipStream_t stream) {
    const float* feats = (const float*)d_in[0];
    const int*   src   = (const int*)d_in[1];
    const int*   dst   = (const int*)d_in[2];
    // d_in[3] = graph_ids: structure is repeat(arange(8000), 20) -> node/20
    const float* W0 = (const float*)d_in[4];
    const float* b0 = (const float*)d_in[5];
    const float* g0 = (const float*)d_in[6];
    const float* be0 = (const float*)d_in[7];
    const float* W1 = (const float*)d_in[8];
    const float* b1 = (const float*)d_in[9];
    const float* g1 = (const float*)d_in[10];
    const float* be1 = (const float*)d_in[11];
    const float* W2 = (const float*)d_in[12];
    const float* b2 = (const float*)d_in[13];
    const float* g2 = (const float*)d_in[14];
    const float* be2 = (const float*)d_in[15];
    const float* Wng = (const float*)d_in[16];
    const float* bng = (const float*)d_in[17];
    const float* Wtr = (const float*)d_in[18];
    const float* btr = (const float*)d_in[19];
    float* out = (float*)d_out;

    char* ws = (char*)d_ws;
    int*    degcnt  = (int*)(ws + OFF_DEGCNT);
    int*    cursor  = (int*)(ws + OFF_CURSOR);
    int*    bcnt    = (int*)(ws + OFF_BCNT);
    float*  spart   = (float*)(ws + OFF_SPART);   // [3][256][128]
    int*    row_ptr = (int*)(ws + OFF_ROWPTR);
    int*    blksum  = (int*)(ws + OFF_BLKSUM);
    int*    col     = (int*)(ws + OFF_COL);
    int*    blist   = (int*)(ws + OFF_BLIST);
    float*  afc     = (float*)(ws + OFF_AFC);     // [3][2][64]
    float*  Wng2    = (float*)(ws + OFF_WNG2);
    float*  bng2    = (float*)(ws + OFF_BNG2);
    float*  Z0      = (float*)(ws + OFF_Z0);
    float*  Z1      = (float*)(ws + OFF_Z1);
    float*  Z2      = Z0;   // layer2 output reuses Z0 (layer0 output dead by then)

    hipMemsetAsync(d_ws, 0, ZERO_BYTES, stream);

    k_degree<<<NE / 256, 256, 0, stream>>>(dst, degcnt);
    k_scan1<<<157, 1024, 0, stream>>>(degcnt, row_ptr, blksum);
    k_scan2<<<1, 256, 0, stream>>>(blksum, 157);
    k_scan3<<<157, 1024, 0, stream>>>(row_ptr, blksum);
    k_bucket<<<NN / 256, 256, 0, stream>>>(degcnt, bcnt, blist);
    k_fill<<<NE / 256, 256, 0, stream>>>(src, dst, row_ptr, cursor, col);

    const int layer_grid = 10 * BPB;
    k_layer<74, false><<<layer_grid, 256, 0, stream>>>(
        feats, 74, nullptr, row_ptr, col, bcnt, blist, W0, b0, Z0, spart);
    k_bn<<<1, 64, 0, stream>>>(spart, g0, be0, afc);
    k_layer<63, true><<<layer_grid, 256, 0, stream>>>(
        Z0, ZST, afc, row_ptr, col, bcnt, blist, W1, b1, Z1, spart + 256 * 128);
    k_bn<<<1, 64, 0, stream>>>(spart + 256 * 128, g1, be1, afc + 128);
    k_layer<63, true><<<layer_grid, 256, 0, stream>>>(
        Z1, ZST, afc + 128, row_ptr, col, bcnt, blist, W2, b2, Z2, spart + 2 * 256 * 128);
    k_bn<<<1, 64, 0, stream>>>(spart + 2 * 256 * 128, g2, be2, afc + 256);

    k_fold<<<1, 128, 0, stream>>>(Wng, bng, afc + 256, Wng2, bng2);
    k_graph<<<NG / 8, 256, 0, stream>>>(Z2, Wng2, bng2, Wtr, btr, out);
}

// Round 2
// 2077.059 us; speedup vs baseline: 1.3259x; 1.3259x over previous
//
#include <hip/hip_runtime.h>
#include <stdint.h>
#include <math.h>

// ---------------- problem constants ----------------
static constexpr int NN = 160000;   // nodes
static constexpr int NE = 640000;   // edges
static constexpr int NG = 8000;     // graphs (20 nodes each, contiguous)
static constexpr int FI0 = 74;      // input feats
static constexpr int FH  = 63;      // hidden
static constexpr int ZST = 64;      // padded z row stride (floats)
static constexpr int NB  = 16;      // nodes per block in layer kernel
static constexpr int BPB = (NN + NB - 1) / NB;   // blocks per bucket = 10000

// ---------------- workspace layout (bytes) ----------------
static constexpr size_t OFF_DEGCNT = 0;                       // 160000 i32
static constexpr size_t OFF_CURSOR = 640000;                  // 160000 i32
static constexpr size_t OFF_BCNT   = 1280000;                 // 16 i32
static constexpr size_t OFF_SPART  = 1280064;                 // 3*256*128 f32 partial stats
static constexpr size_t ZERO_BYTES = 1673280;                 // everything above zeroed
static constexpr size_t OFF_ROWPTR = 1673280;                 // 160001 i32
static constexpr size_t OFF_BLKSUM = 2313472;                 // 512 i32
static constexpr size_t OFF_COL    = 2315520;                 // 640000 i32
static constexpr size_t OFF_BLIST  = 4875520;                 // 10*160000 i32
static constexpr size_t OFF_AFC    = 11275520;                // 3*2*64 f32 (a,c per layer)
static constexpr size_t OFF_WNG2   = 11277056;                // 63*128 f32 folded W_ng
static constexpr size_t OFF_BNG2   = 11309312;                // 128 f32 folded b_ng
static constexpr size_t OFF_Z0     = 11310080;                // 160000*64 f32
static constexpr size_t OFF_Z1     = 52270080;                // 160000*64 f32
// total ~93.2 MB

// ---------------- CSR / degree build ----------------
__global__ void k_degree(const int* __restrict__ dst, int* __restrict__ degcnt) {
    int e = blockIdx.x * 256 + threadIdx.x;
    if (e < NE) atomicAdd(&degcnt[dst[e]], 1);
}

__global__ void k_scan1(const int* __restrict__ degcnt, int* __restrict__ row_ptr,
                        int* __restrict__ blksum) {
    __shared__ int s[1024];
    int t = threadIdx.x;
    int i = blockIdx.x * 1024 + t;
    int v = (i < NN) ? degcnt[i] : 0;
    s[t] = v; __syncthreads();
    for (int off = 1; off < 1024; off <<= 1) {
        int x = (t >= off) ? s[t - off] : 0;
        __syncthreads();
        s[t] += x;
        __syncthreads();
    }
    if (i < NN) row_ptr[i + 1] = s[t];            // local inclusive scan
    if (t == 1023) blksum[blockIdx.x] = s[t];     // block total
}

__global__ void k_scan2(int* __restrict__ blksum, int nblk) {
    __shared__ int s[256];
    int t = threadIdx.x;
    int v = (t < nblk) ? blksum[t] : 0;
    s[t] = v; __syncthreads();
    for (int off = 1; off < 256; off <<= 1) {
        int x = (t >= off) ? s[t - off] : 0;
        __syncthreads();
        s[t] += x;
        __syncthreads();
    }
    if (t < nblk) blksum[t] = s[t] - v;           // exclusive
}

__global__ void k_scan3(int* __restrict__ row_ptr, const int* __restrict__ blksum) {
    int t = threadIdx.x;
    int i = blockIdx.x * 1024 + t;
    if (i < NN) row_ptr[i + 1] += blksum[blockIdx.x];
    if (i == 0) row_ptr[0] = 0;
}

// LDS-aggregated bucket build: 1024-thread blocks, per-block histogram in LDS,
// ONE global atomic per (block, bucket) instead of one per node.
// R0->R1: the per-node version was 649 us (160k atomics on 10 addresses).
__global__ void __launch_bounds__(1024) k_bucket(
        const int* __restrict__ degcnt, int* __restrict__ bcnt,
        int* __restrict__ blist) {
    __shared__ int scnt[10], sbase[10];
    int tid = threadIdx.x;
    if (tid < 10) scnt[tid] = 0;
    __syncthreads();
    int n = blockIdx.x * 1024 + tid;
    int k = 0, pos = 0;
    bool v = (n < NN);
    if (v) {
        int d = degcnt[n];
        k = (d < 1) ? 0 : ((d > 10) ? 9 : d - 1);   // clip(deg,1,10)-1
        pos = atomicAdd(&scnt[k], 1);               // LDS atomic
    }
    __syncthreads();
    if (tid < 10) sbase[tid] = scnt[tid] ? atomicAdd(&bcnt[tid], scnt[tid]) : 0;
    __syncthreads();
    if (v) blist[k * NN + sbase[k] + pos] = n;
}

__global__ void k_fill(const int* __restrict__ src, const int* __restrict__ dst,
                       const int* __restrict__ row_ptr, int* __restrict__ cursor,
                       int* __restrict__ col) {
    int e = blockIdx.x * 256 + threadIdx.x;
    if (e >= NE) return;
    int d = dst[e];
    int pos = row_ptr[d] + atomicAdd(&cursor[d], 1);
    col[pos] = src[e];
}

// ---------------- NF layer: gather + bucketed matmul + relu + stats ----------------
// block = 256 threads = 4 waves; NB=16 nodes (same degree bucket), 4 per wave.
// grid = 10 * BPB; blocks past a bucket's count exit immediately.
template<int FI, bool AFF>
__global__ void __launch_bounds__(256) k_layer(
    const float* __restrict__ in, int in_stride,
    const float* __restrict__ aff,                 // [2][64]: a, c (folded BN of prev layer)
    const int* __restrict__ row_ptr, const int* __restrict__ col,
    const int* __restrict__ bcnt, const int* __restrict__ blist,
    const float* __restrict__ W,                   // [10][FI][63]
    const float* __restrict__ B,                   // [10][63]
    float* __restrict__ zout,                      // [NN][64] (relu'd, pre-BN)
    float* __restrict__ spart)                     // [256][128] f32 partial stats
{
    int bucket = blockIdx.x / BPB;
    int base   = (blockIdx.x % BPB) * NB;
    int cnt    = bcnt[bucket];
    if (base >= cnt) return;

    __shared__ float sW[FI * 63 + 64];
    __shared__ float sTot[4][80][4];
    __shared__ float sRed[2][4][64];

    int tid = threadIdx.x;
    const float* Wk = W + (size_t)bucket * FI * 63;
    for (int i = tid; i < FI * 63; i += 256) sW[i] = Wk[i];
    __syncthreads();

    int wave = tid >> 6, lane = tid & 63;

    int  nidx[4];
    bool val[4];

    // ---- gather phase: tot = self + sum(neighbors) (+ folded BN affine) ----
    for (int t = 0; t < 4; ++t) {
        int idx = base + wave * 4 + t;
        val[t] = (idx < cnt);
        int n = blist[bucket * NN + (val[t] ? idx : (cnt - 1))];
        nidx[t] = n;
        int rs = row_ptr[n], re = row_ptr[n + 1];
        float t0 = 0.f, t1 = 0.f;
        if (lane < FI)      t0 = in[(size_t)n * in_stride + lane];
        if (FI > 64 && lane + 64 < FI) t1 = in[(size_t)n * in_stride + lane + 64];
        for (int e = rs; e < re; ++e) {
            int s = col[e];
            if (lane < FI)      t0 += in[(size_t)s * in_stride + lane];
            if (FI > 64 && lane + 64 < FI) t1 += in[(size_t)s * in_stride + lane + 64];
        }
        if constexpr (AFF) {
            // tot = a*(z_self + sum z_src) + (deg+1)*c
            float dp1 = (float)(re - rs) + 1.0f;
            if (lane < FI) t0 = aff[lane] * t0 + dp1 * aff[64 + lane];
        }
        sTot[wave][lane][t] = t0;
        if (FI > 64 && lane + 64 < FI) sTot[wave][lane + 64][t] = t1;
    }
    // same-wave LDS write->read: compiler inserts lgkmcnt waits; no barrier needed.

    // ---- matmul: z[o] = b[k][o] + sum_j tot[j]*W[k][j][o], 4 nodes at once ----
    float bterm = (lane < 63) ? B[bucket * 63 + lane] : 0.f;
    float acc[4] = {bterm, bterm, bterm, bterm};
    for (int j = 0; j < FI; ++j) {
        float w = sW[j * 63 + lane];  // lane 63 reads pad garbage; result unused
        float4 tv = *reinterpret_cast<const float4*>(&sTot[wave][j][0]);
        acc[0] = fmaf(tv.x, w, acc[0]);
        acc[1] = fmaf(tv.y, w, acc[1]);
        acc[2] = fmaf(tv.z, w, acc[2]);
        acc[3] = fmaf(tv.w, w, acc[3]);
    }

    // ---- relu, store, per-lane (=per-feature) stats ----
    float lsum = 0.f, lsq = 0.f;
    for (int t = 0; t < 4; ++t) {
        float z = fmaxf(acc[t], 0.f);
        if (val[t] && lane < 63) {
            zout[(size_t)nidx[t] * ZST + lane] = z;
            lsum += z; lsq += z * z;
        }
    }
    sRed[0][wave][lane] = lsum;
    sRed[1][wave][lane] = lsq;
    __syncthreads();
    if (wave == 0 && lane < 63) {
        float s = sRed[0][0][lane] + sRed[0][1][lane] + sRed[0][2][lane] + sRed[0][3][lane];
        float q = sRed[1][0][lane] + sRed[1][1][lane] + sRed[1][2][lane] + sRed[1][3][lane];
        float* sp = spart + (size_t)(blockIdx.x & 255) * 128;
        atomicAdd(&sp[lane], s);
        atomicAdd(&sp[64 + lane], q);
    }
}

// ---------------- BN stats -> affine (a, c) ----------------
__global__ void k_bn(const float* __restrict__ spart, const float* __restrict__ gamma,
                     const float* __restrict__ beta, float* __restrict__ afc) {
    int o = threadIdx.x;
    if (o >= 63) return;
    double s = 0.0, q = 0.0;
    for (int cp = 0; cp < 256; ++cp) {
        s += (double)spart[cp * 128 + o];
        q += (double)spart[cp * 128 + 64 + o];
    }
    double mu  = s / NN;
    double var = q / NN - mu * mu;
    float a = (float)((double)gamma[o] / sqrt(var + 1e-5));
    float c = (float)((double)beta[o] - mu * (double)a);
    afc[o] = a;
    afc[64 + o] = c;
}

// ---------------- fold last BN into W_ng ----------------
__global__ void k_fold(const float* __restrict__ W_ng, const float* __restrict__ b_ng,
                       const float* __restrict__ afc2, float* __restrict__ Wng2,
                       float* __restrict__ bng2) {
    int o = threadIdx.x;   // 128
    float acc = b_ng[o];
    for (int j = 0; j < 63; ++j) {
        float w = W_ng[j * 128 + o];
        Wng2[j * 128 + o] = afc2[j] * w;
        acc = fmaf(afc2[64 + j], w, acc);
    }
    bng2[o] = acc;
}

// ---------------- readout: node->graph GEMM + sum/max + tanh + final GEMM ----------------
// block = 256 threads handles 8 graphs (160 nodes). grid = 1000.
__global__ void __launch_bounds__(256) k_graph(
    const float* __restrict__ Z2, const float* __restrict__ Wng2,
    const float* __restrict__ bng2, const float* __restrict__ W_tr,
    const float* __restrict__ b_tr, float* __restrict__ out)
{
    __shared__ float sWng[63 * 128];
    __shared__ float sT[8][256];
    int tid = threadIdx.x;
    for (int i = tid; i < 63 * 128; i += 256) sWng[i] = Wng2[i];
    __syncthreads();

    int wv = tid >> 6, lane = tid & 63;
    int g0 = blockIdx.x * 8;

    // phase A: each wave does 2 graphs; lane covers o and o+64 of 128 outputs
    for (int gg = 0; gg < 2; ++gg) {
        int gl = wv * 2 + gg;
        const float* zb = Z2 + (size_t)(g0 + gl) * 20 * ZST;
        float acc0[20], acc1[20];
        float b0v = bng2[lane], b1v = bng2[lane + 64];
#pragma unroll
        for (int i = 0; i < 20; ++i) { acc0[i] = b0v; acc1[i] = b1v; }
        for (int j = 0; j < 63; ++j) {
            float w0 = sWng[j * 128 + lane];
            float w1 = sWng[j * 128 + lane + 64];
#pragma unroll
            for (int i = 0; i < 20; ++i) {
                float z = zb[i * ZST + j];   // uniform across lanes -> scalar loads
                acc0[i] = fmaf(z, w0, acc0[i]);
                acc1[i] = fmaf(z, w1, acc1[i]);
            }
        }
        float s0 = 0.f, s1 = 0.f, m0 = -1e30f, m1 = -1e30f;
#pragma unroll
        for (int i = 0; i < 20; ++i) {
            s0 += acc0[i]; s1 += acc1[i];
            m0 = fmaxf(m0, acc0[i]); m1 = fmaxf(m1, acc1[i]);
        }
        sT[gl][lane]       = tanhf(s0);
        sT[gl][lane + 64]  = tanhf(s1);
        sT[gl][128 + lane] = tanhf(m0);
        sT[gl][192 + lane] = tanhf(m1);
    }
    __syncthreads();

    // phase B: out[g][d] = b_tr[d] + sum_q t[g][q] * W_tr[q][d]
    int d = tid;
    float acc[8];
    float bt = b_tr[d];
#pragma unroll
    for (int gl = 0; gl < 8; ++gl) acc[gl] = bt;
    for (int q = 0; q < 256; ++q) {
        float w = W_tr[q * 256 + d];
#pragma unroll
        for (int gl = 0; gl < 8; ++gl) acc[gl] = fmaf(sT[gl][q], w, acc[gl]);
    }
#pragma unroll
    for (int gl = 0; gl < 8; ++gl) out[(size_t)(g0 + gl) * 256 + d] = acc[gl];
}

// ---------------- launch ----------------
extern "C" void kernel_launch(void* const* d_in, const int* in_sizes, int n_in,
                              void* d_out, int out_size, void* d_ws, size_t ws_size,
                              hipStream_t stream) {
    const float* feats = (const float*)d_in[0];
    const int*   src   = (const int*)d_in[1];
    const int*   dst   = (const int*)d_in[2];
    // d_in[3] = graph_ids: structure is repeat(arange(8000), 20) -> node/20
    const float* W0 = (const float*)d_in[4];
    const float* b0 = (const float*)d_in[5];
    const float* g0 = (const float*)d_in[6];
    const float* be0 = (const float*)d_in[7];
    const float* W1 = (const float*)d_in[8];
    const float* b1 = (const float*)d_in[9];
    const float* g1 = (const float*)d_in[10];
    const float* be1 = (const float*)d_in[11];
    const float* W2 = (const float*)d_in[12];
    const float* b2 = (const float*)d_in[13];
    const float* g2 = (const float*)d_in[14];
    const float* be2 = (const float*)d_in[15];
    const float* Wng = (const float*)d_in[16];
    const float* bng = (const float*)d_in[17];
    const float* Wtr = (const float*)d_in[18];
    const float* btr = (const float*)d_in[19];
    float* out = (float*)d_out;

    char* ws = (char*)d_ws;
    int*    degcnt  = (int*)(ws + OFF_DEGCNT);
    int*    cursor  = (int*)(ws + OFF_CURSOR);
    int*    bcnt    = (int*)(ws + OFF_BCNT);
    float*  spart   = (float*)(ws + OFF_SPART);   // [3][256][128]
    int*    row_ptr = (int*)(ws + OFF_ROWPTR);
    int*    blksum  = (int*)(ws + OFF_BLKSUM);
    int*    col     = (int*)(ws + OFF_COL);
    int*    blist   = (int*)(ws + OFF_BLIST);
    float*  afc     = (float*)(ws + OFF_AFC);     // [3][2][64]
    float*  Wng2    = (float*)(ws + OFF_WNG2);
    float*  bng2    = (float*)(ws + OFF_BNG2);
    float*  Z0      = (float*)(ws + OFF_Z0);
    float*  Z1      = (float*)(ws + OFF_Z1);
    float*  Z2      = Z0;   // layer2 output reuses Z0 (layer0 output dead by then)

    hipMemsetAsync(d_ws, 0, ZERO_BYTES, stream);

    k_degree<<<NE / 256, 256, 0, stream>>>(dst, degcnt);
    k_scan1<<<157, 1024, 0, stream>>>(degcnt, row_ptr, blksum);
    k_scan2<<<1, 256, 0, stream>>>(blksum, 157);
    k_scan3<<<157, 1024, 0, stream>>>(row_ptr, blksum);
    k_bucket<<<157, 1024, 0, stream>>>(degcnt, bcnt, blist);
    k_fill<<<NE / 256, 256, 0, stream>>>(src, dst, row_ptr, cursor, col);

    const int layer_grid = 10 * BPB;
    k_layer<74, false><<<layer_grid, 256, 0, stream>>>(
        feats, 74, nullptr, row_ptr, col, bcnt, blist, W0, b0, Z0, spart);
    k_bn<<<1, 64, 0, stream>>>(spart, g0, be0, afc);
    k_layer<63, true><<<layer_grid, 256, 0, stream>>>(
        Z0, ZST, afc, row_ptr, col, bcnt, blist, W1, b1, Z1, spart + 256 * 128);
    k_bn<<<1, 64, 0, stream>>>(spart + 256 * 128, g1, be1, afc + 128);
    k_layer<63, true><<<layer_grid, 256, 0, stream>>>(
        Z1, ZST, afc + 128, row_ptr, col, bcnt, blist, W2, b2, Z2, spart + 2 * 256 * 128);
    k_bn<<<1, 64, 0, stream>>>(spart + 2 * 256 * 128, g2, be2, afc + 256);

    k_fold<<<1, 128, 0, stream>>>(Wng, bng, afc + 256, Wng2, bng2);
    k_graph<<<NG / 8, 256, 0, stream>>>(Z2, Wng2, bng2, Wtr, btr, out);
}

// Round 3
// 1130.695 us; speedup vs baseline: 2.4356x; 1.8370x over previous
//
#include <hip/hip_runtime.h>
#include <stdint.h>
#include <math.h>

// ---------------- problem constants ----------------
static constexpr int NN = 160000;   // nodes
static constexpr int NE = 640000;   // edges
static constexpr int NG = 8000;     // graphs (20 nodes each, contiguous)
static constexpr int FH  = 63;      // hidden
static constexpr int ZST = 64;      // padded z row stride (floats)
static constexpr int NB  = 16;      // nodes per block in layer kernel
static constexpr int LGRID = 10016; // >= sum_k ceil(cnt_k/NB) <= 10009

// ---------------- workspace layout (bytes) ----------------
static constexpr size_t OFF_DEGCNT = 0;                       // 160000 i32
static constexpr size_t OFF_CURSOR = 640000;                  // 160000 i32
static constexpr size_t OFF_BCNT   = 1280000;                 // 16 i32
static constexpr size_t OFF_SPART  = 1280064;                 // 3*256*128 f32 partial stats
static constexpr size_t ZERO_BYTES = 1673280;                 // everything above zeroed
static constexpr size_t OFF_ROWPTR = 1673280;                 // 160001 i32
static constexpr size_t OFF_BLKSUM = 2313472;                 // 512 i32
static constexpr size_t OFF_COL    = 2315520;                 // 640000 i32
static constexpr size_t OFF_BLIST  = 4875520;                 // 10*160000 i32
static constexpr size_t OFF_AFC    = 11275520;                // 3*2*64 f32 (a,c per layer)
static constexpr size_t OFF_WNG2   = 11277056;                // 63*128 f32 folded W_ng
static constexpr size_t OFF_BNG2   = 11309312;                // 128 f32 folded b_ng
static constexpr size_t OFF_PBLK   = 11309824;                // 11 i32 block-prefix table
static constexpr size_t OFF_Z0     = 11310080;                // 160000*64 f32
static constexpr size_t OFF_Z1     = 52270080;                // 160000*64 f32

// ---------------- CSR / degree build ----------------
__global__ void k_degree(const int* __restrict__ dst, int* __restrict__ degcnt) {
    int e = blockIdx.x * 256 + threadIdx.x;
    if (e < NE) atomicAdd(&degcnt[dst[e]], 1);
}

__global__ void k_scan1(const int* __restrict__ degcnt, int* __restrict__ row_ptr,
                        int* __restrict__ blksum) {
    __shared__ int s[1024];
    int t = threadIdx.x;
    int i = blockIdx.x * 1024 + t;
    int v = (i < NN) ? degcnt[i] : 0;
    s[t] = v; __syncthreads();
    for (int off = 1; off < 1024; off <<= 1) {
        int x = (t >= off) ? s[t - off] : 0;
        __syncthreads();
        s[t] += x;
        __syncthreads();
    }
    if (i < NN) row_ptr[i + 1] = s[t];
    if (t == 1023) blksum[blockIdx.x] = s[t];
}

__global__ void k_scan2(int* __restrict__ blksum, int nblk) {
    __shared__ int s[256];
    int t = threadIdx.x;
    int v = (t < nblk) ? blksum[t] : 0;
    s[t] = v; __syncthreads();
    for (int off = 1; off < 256; off <<= 1) {
        int x = (t >= off) ? s[t - off] : 0;
        __syncthreads();
        s[t] += x;
        __syncthreads();
    }
    if (t < nblk) blksum[t] = s[t] - v;
}

__global__ void k_scan3(int* __restrict__ row_ptr, const int* __restrict__ blksum) {
    int t = threadIdx.x;
    int i = blockIdx.x * 1024 + t;
    if (i < NN) row_ptr[i + 1] += blksum[blockIdx.x];
    if (i == 0) row_ptr[0] = 0;
}

// LDS-aggregated bucket build (R1: one global atomic per (block,bucket))
__global__ void __launch_bounds__(1024) k_bucket(
        const int* __restrict__ degcnt, int* __restrict__ bcnt,
        int* __restrict__ blist) {
    __shared__ int scnt[10], sbase[10];
    int tid = threadIdx.x;
    if (tid < 10) scnt[tid] = 0;
    __syncthreads();
    int n = blockIdx.x * 1024 + tid;
    int k = 0, pos = 0;
    bool v = (n < NN);
    if (v) {
        int d = degcnt[n];
        k = (d < 1) ? 0 : ((d > 10) ? 9 : d - 1);
        pos = atomicAdd(&scnt[k], 1);
    }
    __syncthreads();
    if (tid < 10) sbase[tid] = scnt[tid] ? atomicAdd(&bcnt[tid], scnt[tid]) : 0;
    __syncthreads();
    if (v) blist[k * NN + sbase[k] + pos] = n;
}

// prefix of per-bucket block counts -> pblk[0..10]
__global__ void k_prep(const int* __restrict__ bcnt, int* __restrict__ pblk) {
    if (threadIdx.x == 0) {
        int s = 0; pblk[0] = 0;
        for (int k = 0; k < 10; ++k) { s += (bcnt[k] + NB - 1) / NB; pblk[k + 1] = s; }
    }
}

__global__ void k_fill(const int* __restrict__ src, const int* __restrict__ dst,
                       const int* __restrict__ row_ptr, int* __restrict__ cursor,
                       int* __restrict__ col) {
    int e = blockIdx.x * 256 + threadIdx.x;
    if (e >= NE) return;
    int d = dst[e];
    int pos = row_ptr[d] + atomicAdd(&cursor[d], 1);
    col[pos] = src[e];
}

// ---------------- NF layer body, templated on bucket (=> compile-time degree) --------
// R2->R3: gather was a serial col->row load chain (eff. ~1.3 outstanding loads/wave,
// VALUBusy 7.5%). Known degree => fully unrolled independent loads.
template<int FI, bool AFF, int BUCKET>
__device__ __forceinline__ void layer_body(
    int base, int cnt,
    const float* __restrict__ in, int in_stride,
    const float* __restrict__ aff,
    const int* __restrict__ row_ptr, const int* __restrict__ col,
    const int* __restrict__ blist,
    const float* __restrict__ W, const float* __restrict__ B,
    float* __restrict__ zout, float* __restrict__ spart,
    float* sW, float (*sTot)[80][4], float (*sRed)[4][64])
{
    int tid = threadIdx.x;
    const float* Wk = W + (size_t)BUCKET * FI * 63;
    for (int i = tid; i < FI * 63; i += 256) sW[i] = Wk[i];
    __syncthreads();

    int wave = tid >> 6, lane = tid & 63;
    bool lo = (lane < FI);
    bool hi = (FI > 64) && (lane + 64 < FI);

    int nidx[4]; bool val[4]; int rs[4], dg[4];
#pragma unroll
    for (int t = 0; t < 4; ++t) {
        int idx = base + wave * 4 + t;
        val[t] = (idx < cnt);
        int n = blist[BUCKET * NN + (val[t] ? idx : (cnt - 1))];
        nidx[t] = n;
        rs[t] = row_ptr[n];
        dg[t] = row_ptr[n + 1] - rs[t];
    }
    float a0[4], a1[4];
#pragma unroll
    for (int t = 0; t < 4; ++t) {
        const float* rp = in + (size_t)nidx[t] * in_stride;
        a0[t] = lo ? rp[lane] : 0.f;
        a1[t] = hi ? rp[lane + 64] : 0.f;
    }

    if constexpr (BUCKET == 0) {
        // deg 0 or 1, predicated single edge
#pragma unroll
        for (int t = 0; t < 4; ++t) {
            int c = col[(dg[t] > 0) ? rs[t] : 0];
            const float* rp = in + (size_t)c * in_stride;
            if (dg[t] > 0) {
                a0[t] += lo ? rp[lane] : 0.f;
                a1[t] += hi ? rp[lane + 64] : 0.f;
            }
        }
    } else if constexpr (BUCKET <= 8) {
        constexpr int DEG = BUCKET + 1;
        int cidx[4][DEG];
#pragma unroll
        for (int t = 0; t < 4; ++t)
#pragma unroll
            for (int d = 0; d < DEG; ++d) cidx[t][d] = col[rs[t] + d];
#pragma unroll
        for (int d = 0; d < DEG; ++d) {
            float v0[4], v1[4];
#pragma unroll
            for (int t = 0; t < 4; ++t) {
                const float* rp = in + (size_t)cidx[t][d] * in_stride;
                v0[t] = lo ? rp[lane] : 0.f;
                v1[t] = hi ? rp[lane + 64] : 0.f;
            }
#pragma unroll
            for (int t = 0; t < 4; ++t) { a0[t] += v0[t]; a1[t] += v1[t]; }
        }
    } else {
        // BUCKET 9: deg >= 10. 10 unrolled + rare dynamic tail.
        int cidx[4][10];
#pragma unroll
        for (int t = 0; t < 4; ++t)
#pragma unroll
            for (int d = 0; d < 10; ++d) cidx[t][d] = col[rs[t] + d];
#pragma unroll
        for (int d = 0; d < 10; ++d) {
            float v0[4], v1[4];
#pragma unroll
            for (int t = 0; t < 4; ++t) {
                const float* rp = in + (size_t)cidx[t][d] * in_stride;
                v0[t] = lo ? rp[lane] : 0.f;
                v1[t] = hi ? rp[lane + 64] : 0.f;
            }
#pragma unroll
            for (int t = 0; t < 4; ++t) { a0[t] += v0[t]; a1[t] += v1[t]; }
        }
        int mx = max(max(dg[0], dg[1]), max(dg[2], dg[3]));
        for (int d = 10; d < mx; ++d) {
#pragma unroll
            for (int t = 0; t < 4; ++t) {
                if (d < dg[t]) {
                    int c = col[rs[t] + d];
                    const float* rp = in + (size_t)c * in_stride;
                    a0[t] += lo ? rp[lane] : 0.f;
                    a1[t] += hi ? rp[lane + 64] : 0.f;
                }
            }
        }
    }

#pragma unroll
    for (int t = 0; t < 4; ++t) {
        if constexpr (AFF) {
            // tot = a*(y_self + sum y_nb) + (deg+1)*c
            if (lo) a0[t] = aff[lane] * a0[t] + (float)(dg[t] + 1) * aff[64 + lane];
        }
        sTot[wave][lane][t] = a0[t];
        if (hi) sTot[wave][lane + 64][t] = a1[t];
    }
    // same-wave LDS write->read: compiler inserts lgkmcnt waits; no barrier needed.

    float bterm = (lane < 63) ? B[BUCKET * 63 + lane] : 0.f;
    float acc[4] = {bterm, bterm, bterm, bterm};
    for (int j = 0; j < FI; ++j) {
        float w = sW[j * 63 + lane];  // lane 63 reads pad garbage; result unused
        float4 tv = *reinterpret_cast<const float4*>(&sTot[wave][j][0]);
        acc[0] = fmaf(tv.x, w, acc[0]);
        acc[1] = fmaf(tv.y, w, acc[1]);
        acc[2] = fmaf(tv.z, w, acc[2]);
        acc[3] = fmaf(tv.w, w, acc[3]);
    }

    float lsum = 0.f, lsq = 0.f;
#pragma unroll
    for (int t = 0; t < 4; ++t) {
        float z = fmaxf(acc[t], 0.f);
        if (val[t] && lane < 63) {
            zout[(size_t)nidx[t] * ZST + lane] = z;
            lsum += z; lsq += z * z;
        }
    }
    sRed[0][wave][lane] = lsum;
    sRed[1][wave][lane] = lsq;
    __syncthreads();
    if (wave == 0 && lane < 63) {
        float s = sRed[0][0][lane] + sRed[0][1][lane] + sRed[0][2][lane] + sRed[0][3][lane];
        float q = sRed[1][0][lane] + sRed[1][1][lane] + sRed[1][2][lane] + sRed[1][3][lane];
        float* sp = spart + (size_t)(blockIdx.x & 255) * 128;
        atomicAdd(&sp[lane], s);
        atomicAdd(&sp[64 + lane], q);
    }
}

template<int FI, bool AFF>
__global__ void __launch_bounds__(256) k_layer(
    const float* __restrict__ in, int in_stride,
    const float* __restrict__ aff,
    const int* __restrict__ row_ptr, const int* __restrict__ col,
    const int* __restrict__ bcnt, const int* __restrict__ blist,
    const int* __restrict__ pblk,
    const float* __restrict__ W, const float* __restrict__ B,
    float* __restrict__ zout, float* __restrict__ spart)
{
    __shared__ float sW[FI * 63 + 64];
    __shared__ float sTot[4][80][4];
    __shared__ float sRed[2][4][64];
    int b = blockIdx.x;
    if (b >= pblk[10]) return;
    int k = 0;
#pragma unroll
    for (int i = 1; i <= 9; ++i) k += (b >= pblk[i]) ? 1 : 0;
    int base = (b - pblk[k]) * NB;
    int cnt = bcnt[k];
#define CASE(K) case K: layer_body<FI, AFF, K>(base, cnt, in, in_stride, aff, row_ptr, col, \
    blist, W, B, zout, spart, sW, sTot, sRed); break;
    switch (k) {
        CASE(0) CASE(1) CASE(2) CASE(3) CASE(4)
        CASE(5) CASE(6) CASE(7) CASE(8) CASE(9)
    }
#undef CASE
}

// ---------------- BN stats -> affine (a, c) ----------------
__global__ void k_bn(const float* __restrict__ spart, const float* __restrict__ gamma,
                     const float* __restrict__ beta, float* __restrict__ afc) {
    int o = threadIdx.x;
    if (o >= 63) return;
    double s = 0.0, q = 0.0;
    for (int cp = 0; cp < 256; ++cp) {
        s += (double)spart[cp * 128 + o];
        q += (double)spart[cp * 128 + 64 + o];
    }
    double mu  = s / NN;
    double var = q / NN - mu * mu;
    float a = (float)((double)gamma[o] / sqrt(var + 1e-5));
    float c = (float)((double)beta[o] - mu * (double)a);
    afc[o] = a;
    afc[64 + o] = c;
}

// ---------------- fold last BN into W_ng ----------------
__global__ void k_fold(const float* __restrict__ W_ng, const float* __restrict__ b_ng,
                       const float* __restrict__ afc2, float* __restrict__ Wng2,
                       float* __restrict__ bng2) {
    int o = threadIdx.x;   // 128
    float acc = b_ng[o];
    for (int j = 0; j < 63; ++j) {
        float w = W_ng[j * 128 + o];
        Wng2[j * 128 + o] = afc2[j] * w;
        acc = fmaf(afc2[64 + j], w, acc);
    }
    bng2[o] = acc;
}

// ---------------- readout: node->graph GEMM + sum/max + tanh + final GEMM ----------------
__global__ void __launch_bounds__(256) k_graph(
    const float* __restrict__ Z2, const float* __restrict__ Wng2,
    const float* __restrict__ bng2, const float* __restrict__ W_tr,
    const float* __restrict__ b_tr, float* __restrict__ out)
{
    __shared__ float sWng[63 * 128];
    __shared__ float sT[8][256];
    int tid = threadIdx.x;
    for (int i = tid; i < 63 * 128; i += 256) sWng[i] = Wng2[i];
    __syncthreads();

    int wv = tid >> 6, lane = tid & 63;
    int g0 = blockIdx.x * 8;

    for (int gg = 0; gg < 2; ++gg) {
        int gl = wv * 2 + gg;
        const float* zb = Z2 + (size_t)(g0 + gl) * 20 * ZST;
        float acc0[20], acc1[20];
        float b0v = bng2[lane], b1v = bng2[lane + 64];
#pragma unroll
        for (int i = 0; i < 20; ++i) { acc0[i] = b0v; acc1[i] = b1v; }
        for (int j = 0; j < 63; ++j) {
            float w0 = sWng[j * 128 + lane];
            float w1 = sWng[j * 128 + lane + 64];
#pragma unroll
            for (int i = 0; i < 20; ++i) {
                float z = zb[i * ZST + j];   // uniform across lanes -> scalar loads
                acc0[i] = fmaf(z, w0, acc0[i]);
                acc1[i] = fmaf(z, w1, acc1[i]);
            }
        }
        float s0 = 0.f, s1 = 0.f, m0 = -1e30f, m1 = -1e30f;
#pragma unroll
        for (int i = 0; i < 20; ++i) {
            s0 += acc0[i]; s1 += acc1[i];
            m0 = fmaxf(m0, acc0[i]); m1 = fmaxf(m1, acc1[i]);
        }
        sT[gl][lane]       = tanhf(s0);
        sT[gl][lane + 64]  = tanhf(s1);
        sT[gl][128 + lane] = tanhf(m0);
        sT[gl][192 + lane] = tanhf(m1);
    }
    __syncthreads();

    int d = tid;
    float acc[8];
    float bt = b_tr[d];
#pragma unroll
    for (int gl = 0; gl < 8; ++gl) acc[gl] = bt;
    for (int q = 0; q < 256; ++q) {
        float w = W_tr[q * 256 + d];
#pragma unroll
        for (int gl = 0; gl < 8; ++gl) acc[gl] = fmaf(sT[gl][q], w, acc[gl]);
    }
#pragma unroll
    for (int gl = 0; gl < 8; ++gl) out[(size_t)(g0 + gl) * 256 + d] = acc[gl];
}

// ---------------- launch ----------------
extern "C" void kernel_launch(void* const* d_in, const int* in_sizes, int n_in,
                              void* d_out, int out_size, void* d_ws, size_t ws_size,
                              hipStream_t stream) {
    const float* feats = (const float*)d_in[0];
    const int*   src   = (const int*)d_in[1];
    const int*   dst   = (const int*)d_in[2];
    // d_in[3] = graph_ids: repeat(arange(8000), 20) -> node/20, unused
    const float* W0 = (const float*)d_in[4];
    const float* b0 = (const float*)d_in[5];
    const float* g0 = (const float*)d_in[6];
    const float* be0 = (const float*)d_in[7];
    const float* W1 = (const float*)d_in[8];
    const float* b1 = (const float*)d_in[9];
    const float* g1 = (const float*)d_in[10];
    const float* be1 = (const float*)d_in[11];
    const float* W2 = (const float*)d_in[12];
    const float* b2 = (const float*)d_in[13];
    const float* g2 = (const float*)d_in[14];
    const float* be2 = (const float*)d_in[15];
    const float* Wng = (const float*)d_in[16];
    const float* bng = (const float*)d_in[17];
    const float* Wtr = (const float*)d_in[18];
    const float* btr = (const float*)d_in[19];
    float* out = (float*)d_out;

    char* ws = (char*)d_ws;
    int*    degcnt  = (int*)(ws + OFF_DEGCNT);
    int*    cursor  = (int*)(ws + OFF_CURSOR);
    int*    bcnt    = (int*)(ws + OFF_BCNT);
    float*  spart   = (float*)(ws + OFF_SPART);   // [3][256][128]
    int*    row_ptr = (int*)(ws + OFF_ROWPTR);
    int*    blksum  = (int*)(ws + OFF_BLKSUM);
    int*    col     = (int*)(ws + OFF_COL);
    int*    blist   = (int*)(ws + OFF_BLIST);
    float*  afc     = (float*)(ws + OFF_AFC);     // [3][2][64]
    float*  Wng2    = (float*)(ws + OFF_WNG2);
    float*  bng2    = (float*)(ws + OFF_BNG2);
    int*    pblk    = (int*)(ws + OFF_PBLK);
    float*  Z0      = (float*)(ws + OFF_Z0);
    float*  Z1      = (float*)(ws + OFF_Z1);
    float*  Z2      = Z0;   // layer2 output reuses Z0

    hipMemsetAsync(d_ws, 0, ZERO_BYTES, stream);

    k_degree<<<NE / 256, 256, 0, stream>>>(dst, degcnt);
    k_scan1<<<157, 1024, 0, stream>>>(degcnt, row_ptr, blksum);
    k_scan2<<<1, 256, 0, stream>>>(blksum, 157);
    k_scan3<<<157, 1024, 0, stream>>>(row_ptr, blksum);
    k_bucket<<<157, 1024, 0, stream>>>(degcnt, bcnt, blist);
    k_prep<<<1, 64, 0, stream>>>(bcnt, pblk);
    k_fill<<<NE / 256, 256, 0, stream>>>(src, dst, row_ptr, cursor, col);

    k_layer<74, false><<<LGRID, 256, 0, stream>>>(
        feats, 74, nullptr, row_ptr, col, bcnt, blist, pblk, W0, b0, Z0, spart);
    k_bn<<<1, 64, 0, stream>>>(spart, g0, be0, afc);
    k_layer<63, true><<<LGRID, 256, 0, stream>>>(
        Z0, ZST, afc, row_ptr, col, bcnt, blist, pblk, W1, b1, Z1, spart + 256 * 128);
    k_bn<<<1, 64, 0, stream>>>(spart + 256 * 128, g1, be1, afc + 128);
    k_layer<63, true><<<LGRID, 256, 0, stream>>>(
        Z1, ZST, afc + 128, row_ptr, col, bcnt, blist, pblk, W2, b2, Z2, spart + 2 * 256 * 128);
    k_bn<<<1, 64, 0, stream>>>(spart + 2 * 256 * 128, g2, be2, afc + 256);

    k_fold<<<1, 128, 0, stream>>>(Wng, bng, afc + 256, Wng2, bng2);
    k_graph<<<NG / 8, 256, 0, stream>>>(Z2, Wng2, bng2, Wtr, btr, out);
}